// Round 10
// baseline (320.584 us; speedup 1.0000x reference)
//
#include <hip/hip_runtime.h>

#define D 256
#define B 128
#define S 64
#define L 32
#define K 32
#define KH 16
#define NW 8      // waves per recur block (512 threads), 32 cols/wave
#define NSUB 2    // 2 adjacent cols per lane (col2 remap)
#define HSTR 260  // u16 stride (proven 0-conflict R7/R8)

typedef _Float16 f16x8 __attribute__((ext_vector_type(8)));  // 8 f16 in 4 VGPRs
typedef float f32x4 __attribute__((ext_vector_type(4)));
typedef unsigned short u16;
typedef unsigned int u32;

__device__ __forceinline__ u16 h_bits(_Float16 h) {
    union { _Float16 h; u16 u; } x; x.h = h; return x.u;
}
__device__ __forceinline__ _Float16 f16_bits(u16 v) {
    union { u16 u; _Float16 h; } x; x.u = v; return x.h;
}

// ---------------------------------------------------------------------------
// R19 embed_kernel: R1-proven 2048-block gather (4 sentences/block, 1/wave,
// float4 E rows, wave-uniform mask skip) + fused mask extraction. Each enc
// line written ONCE by one block — this is the fix for R9's ×8 per-XCD
// write-amplification (WRITE_SIZE 124 MB from duplicated enc writes).
// ---------------------------------------------------------------------------
__global__ __launch_bounds__(256) void embed_kernel(
    const int* __restrict__ prgrph, const float* __restrict__ E,
    const void* __restrict__ mraw,
    float* __restrict__ enc, int* __restrict__ mask_out) {
    const int t = threadIdx.x;
    const int g = t >> 6;                // sentence within block (== wave id)
    const int c4 = t & 63;               // float4 column group
    __shared__ int flag;
    __shared__ int smask[4];
    __shared__ int sidx[4][L];
    if (t == 0) flag = 0;
    __syncthreads();
    {   // format detect: same 1024-word scan semantics as old mask_kernel
        const u32* w32 = (const u32*)mraw;
        int loc = 0;
        #pragma unroll
        for (int j = 0; j < 4; ++j)
            if (w32[t * 4 + j] > 1u) loc = 1;
        if (loc) flag = 1;   // benign race
    }
    if (t < 4 * L) sidx[t >> 5][t & 31] = prgrph[(size_t)blockIdx.x * 4 * L + t];
    __syncthreads();
    if (t < 4) {
        const int gi = blockIdx.x * 4 + t;
        const int mv = (flag != 0)
            ? (int)((const unsigned char*)mraw)[(size_t)gi * L]
            : ((const int*)mraw)[(size_t)gi * L];
        smask[t] = mv;
        mask_out[gi] = mv;
    }
    __syncthreads();
    if (!smask[g]) return;               // wave-uniform: g == wave
    const float4* E4 = (const float4*)E;
    float4 a = make_float4(0.f, 0.f, 0.f, 0.f);
    #pragma unroll
    for (int l = 0; l < L; ++l) {
        const float4 v = E4[(size_t)sidx[g][l] * (D / 4) + c4];
        a.x += v.x; a.y += v.y; a.z += v.z; a.w += v.w;
    }
    *(float4*)&enc[(size_t)(blockIdx.x * 4 + g) * D + c4 * 4] = a;
}

// ---------------------------------------------------------------------------
// R19 recur_kernel: R9-VERIFIED MFMA prologue (eW/ek/keysV computed in-block
// from enc/W/V/keys via f16 hi/lo 3-product — passed with identical absmax
// 1.95e-3 in R9) + the R5/R7-proven 91µs recurrence loop reading eWc/ekv
// from LDS. Difference vs R9's failed mega-fusion: NO gather here (enc is
// read, written once by embed_kernel) -> no duplicated writes, no per-XCD
// amplification. W/V/U reads replicate across blocks but are read-only
// (768 KB, L2-resident per XCD; L3 shared).
// Unmasked enc rows are stale workspace -> garbage flows into eWh/ekl rows
// that are never read (loop visits masked steps only). Benign.
// R10-R12: KEEP __syncthreads. setprio negative (lockstep, m190).
// ---------------------------------------------------------------------------
__global__ __launch_bounds__(512, 2) void recur_kernel(
    const float* __restrict__ enc, const float* __restrict__ keys,
    const float* __restrict__ Wm, const float* __restrict__ Vm,
    const float* __restrict__ U, const int* __restrict__ mask,
    float* __restrict__ out) {
    const int b  = blockIdx.x >> 1;
    const int kh = (blockIdx.x & 1) * KH;
    const int t = threadIdx.x;
    const int wave = t >> 6, lane = t & 63;
    const int n = lane & 15, quad = lane >> 4;
    const int col2 = wave * 32 + 2 * n;

    __shared__ u16   hF[2][KH][HSTR];    // 16.6 KB
    __shared__ float redN[2][KH][NW];
    __shared__ float redG[2][KH][NW];
    __shared__ u16   eWh[S][260];        // 33.3 KB, eW rows in f16
    __shared__ float ekl[S][20];         // 5.1 KB

    // ---- keys A/B-frags (entity row/col = n): used by ek (B) and keysV (A)
    f16x8 Kh[8], Kl[8];
    #pragma unroll
    for (int kt = 0; kt < 8; ++kt) {
        #pragma unroll
        for (int j = 0; j < 8; ++j) {
            const float v = keys[(size_t)(b * K + kh + n) * D + kt * 32 + quad * 8 + j];
            const _Float16 vh = (_Float16)v;
            Kh[kt][j] = vh;
            Kl[kt][j] = (_Float16)(v - (float)vh);
        }
    }

    // ---- eW = enc @ W: 4 sentence-tiles x 8 kt x 3 products (R9-verified) ----
    {
        f16x8 Bh[NSUB][8], Bl[NSUB][8];
        #pragma unroll
        for (int sub = 0; sub < NSUB; ++sub) {
            const int col = col2 + sub;
            #pragma unroll
            for (int kt = 0; kt < 8; ++kt) {
                #pragma unroll
                for (int j = 0; j < 8; ++j) {
                    const float w = Wm[(size_t)(kt * 32 + quad * 8 + j) * D + col];
                    const _Float16 wh = (_Float16)w;
                    Bh[sub][kt][j] = wh;
                    Bl[sub][kt][j] = (_Float16)(w - (float)wh);
                }
            }
        }
        #pragma unroll
        for (int tile = 0; tile < 4; ++tile) {
            f32x4 acc[NSUB];
            acc[0] = (f32x4){0.f, 0.f, 0.f, 0.f};
            acc[1] = (f32x4){0.f, 0.f, 0.f, 0.f};
            #pragma unroll
            for (int kt = 0; kt < 8; ++kt) {
                const float* ep = enc + (size_t)(b * S + tile * 16 + n) * D
                                + kt * 32 + quad * 8;
                const float4 e0 = *(const float4*)ep;
                const float4 e1 = *(const float4*)(ep + 4);
                f16x8 ah, al;
                #pragma unroll
                for (int j = 0; j < 8; ++j) {
                    const float v = (j < 4) ? ((const float*)&e0)[j]
                                            : ((const float*)&e1)[j - 4];
                    const _Float16 vh = (_Float16)v;
                    ah[j] = vh;
                    al[j] = (_Float16)(v - (float)vh);
                }
                #pragma unroll
                for (int sub = 0; sub < NSUB; ++sub) {
                    acc[sub] = __builtin_amdgcn_mfma_f32_16x16x32_f16(ah, Bh[sub][kt], acc[sub], 0, 0, 0);
                    acc[sub] = __builtin_amdgcn_mfma_f32_16x16x32_f16(ah, Bl[sub][kt], acc[sub], 0, 0, 0);
                    acc[sub] = __builtin_amdgcn_mfma_f32_16x16x32_f16(al, Bh[sub][kt], acc[sub], 0, 0, 0);
                }
            }
            #pragma unroll
            for (int reg = 0; reg < 4; ++reg) {
                const u32 packed =
                    ((u32)h_bits((_Float16)acc[1][reg]) << 16) |
                    (u32)h_bits((_Float16)acc[0][reg]);
                *(u32*)&eWh[tile * 16 + quad * 4 + reg][col2] = packed;
            }
        }
    }

    // ---- ek = enc @ keys^T (16 local entities; all waves redundant, benign)
    #pragma unroll
    for (int tile = 0; tile < 4; ++tile) {
        f32x4 acc = (f32x4){0.f, 0.f, 0.f, 0.f};
        #pragma unroll
        for (int kt = 0; kt < 8; ++kt) {
            const float* ep = enc + (size_t)(b * S + tile * 16 + n) * D
                            + kt * 32 + quad * 8;
            const float4 e0 = *(const float4*)ep;
            const float4 e1 = *(const float4*)(ep + 4);
            f16x8 ah, al;
            #pragma unroll
            for (int j = 0; j < 8; ++j) {
                const float v = (j < 4) ? ((const float*)&e0)[j]
                                        : ((const float*)&e1)[j - 4];
                const _Float16 vh = (_Float16)v;
                ah[j] = vh;
                al[j] = (_Float16)(v - (float)vh);
            }
            acc = __builtin_amdgcn_mfma_f32_16x16x32_f16(ah, Kh[kt], acc, 0, 0, 0);
            acc = __builtin_amdgcn_mfma_f32_16x16x32_f16(ah, Kl[kt], acc, 0, 0, 0);
            acc = __builtin_amdgcn_mfma_f32_16x16x32_f16(al, Kh[kt], acc, 0, 0, 0);
        }
        #pragma unroll
        for (int reg = 0; reg < 4; ++reg)
            ekl[tile * 16 + quad * 4 + reg][n] = acc[reg];
    }

    // ---- keysV = keys @ V -> keysVc[reg][sub] directly (R9-verified) ----
    float keysVc[4][NSUB];
    {
        f16x8 Vh[NSUB][8], Vl[NSUB][8];
        #pragma unroll
        for (int sub = 0; sub < NSUB; ++sub) {
            const int col = col2 + sub;
            #pragma unroll
            for (int kt = 0; kt < 8; ++kt) {
                #pragma unroll
                for (int j = 0; j < 8; ++j) {
                    const float v = Vm[(size_t)(kt * 32 + quad * 8 + j) * D + col];
                    const _Float16 vh = (_Float16)v;
                    Vh[sub][kt][j] = vh;
                    Vl[sub][kt][j] = (_Float16)(v - (float)vh);
                }
            }
        }
        f32x4 accV[NSUB];
        accV[0] = (f32x4){0.f, 0.f, 0.f, 0.f};
        accV[1] = (f32x4){0.f, 0.f, 0.f, 0.f};
        #pragma unroll
        for (int kt = 0; kt < 8; ++kt) {
            #pragma unroll
            for (int sub = 0; sub < NSUB; ++sub) {
                accV[sub] = __builtin_amdgcn_mfma_f32_16x16x32_f16(Kh[kt], Vh[sub][kt], accV[sub], 0, 0, 0);
                accV[sub] = __builtin_amdgcn_mfma_f32_16x16x32_f16(Kh[kt], Vl[sub][kt], accV[sub], 0, 0, 0);
                accV[sub] = __builtin_amdgcn_mfma_f32_16x16x32_f16(Kl[kt], Vh[sub][kt], accV[sub], 0, 0, 0);
            }
        }
        #pragma unroll
        for (int reg = 0; reg < 4; ++reg) {
            keysVc[reg][0] = accV[0][reg];
            keysVc[reg][1] = accV[1][reg];
        }
    }

    __syncthreads();   // eWh/ekl staged for the loop

    // ---- preload U B-fragments (f16 hi/lo): 128 AGPRs, pinned ----
    f16x8 Uhi[NSUB][8], Ulo[NSUB][8];
    #pragma unroll
    for (int sub = 0; sub < NSUB; ++sub) {
        const int col = col2 + sub;
        #pragma unroll
        for (int kt = 0; kt < 8; ++kt) {
            #pragma unroll
            for (int j = 0; j < 8; ++j) {
                const int k = kt * 32 + quad * 8 + j;
                const float u = U[(size_t)k * D + col];
                const _Float16 uh = (_Float16)u;
                Uhi[sub][kt][j] = uh;
                Ulo[sub][kt][j] = (_Float16)(u - (float)uh);
            }
        }
    }
    #pragma unroll
    for (int sub = 0; sub < NSUB; ++sub)
        #pragma unroll
        for (int kt = 0; kt < 8; ++kt)
            asm volatile("" : "+a"(Uhi[sub][kt]), "+a"(Ulo[sub][kt]));

    // ---- per-lane state ----
    float upv[4][NSUB];
    float rn[4];
    #pragma unroll
    for (int reg = 0; reg < 4; ++reg) {
        rn[reg] = 1.f;
        upv[reg][0] = 0.f; upv[reg][1] = 0.f;
    }

    const int* bm = mask + b * S;
    unsigned long long rem = __ballot(bm[lane] != 0);

    float eWc[NSUB];
    float4 ekv = make_float4(0.f, 0.f, 0.f, 0.f);
    eWc[0] = 0.f; eWc[1] = 0.f;
    if (rem) {
        const int s0 = (int)__builtin_ctzll(rem);
        const u32 w = *(const u32*)&eWh[s0][col2];
        eWc[0] = (float)f16_bits((u16)(w & 0xffff));
        eWc[1] = (float)f16_bits((u16)(w >> 16));
        ekv = *(const float4*)&ekl[s0][quad * 4];
    }

    int p = 0, q = 0;
    bool first = true;
    while (rem) {
        rem &= rem - 1;
        const int sn = rem ? (int)__builtin_ctzll(rem) : -1;

        // ---- issue next-step e load early (covered by MFMA) ----
        float e_n[NSUB];
        e_n[0] = 0.f; e_n[1] = 0.f;
        if (sn >= 0) {
            const float2 e2 = *(const float2*)&enc[(size_t)(b * S + sn) * D + col2];
            e_n[0] = e2.x; e_n[1] = e2.y;
        }

        // ---- MFMA: acc = h_prev @ (Uhi,Ulo), 4 indep chains of 8 ----
        f32x4 acc[NSUB][2];
        #pragma unroll
        for (int sub = 0; sub < NSUB; ++sub) {
            acc[sub][0] = (f32x4){0.f, 0.f, 0.f, 0.f};
            acc[sub][1] = (f32x4){0.f, 0.f, 0.f, 0.f};
        }
        if (!first) {
            #pragma unroll
            for (int kt = 0; kt < 8; ++kt) {
                const f16x8 av = *(const f16x8*)&hF[p][n][kt * 32 + quad * 8];
                #pragma unroll
                for (int sub = 0; sub < NSUB; ++sub) {
                    acc[sub][0] = __builtin_amdgcn_mfma_f32_16x16x32_f16(av, Uhi[sub][kt], acc[sub][0], 0, 0, 0);
                    acc[sub][1] = __builtin_amdgcn_mfma_f32_16x16x32_f16(av, Ulo[sub][kt], acc[sub][1], 0, 0, 0);
                }
            }
        }

        // ---- gate ----
        float gate[4];
        #pragma unroll
        for (int reg = 0; reg < 4; ++reg) {
            const float ekb = (reg == 0) ? ekv.x : (reg == 1) ? ekv.y
                            : (reg == 2) ? ekv.z : ekv.w;
            float g = ekb;
            if (!first) {
                const float* rg = redG[q ^ 1][quad * 4 + reg];
                const float4 g0 = *(const float4*)rg;
                const float4 g1 = *(const float4*)(rg + 4);
                g += rn[reg] * (g0.x + g0.y + g0.z + g0.w +
                                g1.x + g1.y + g1.z + g1.w);
            }
            gate[reg] = 1.f / (1.f + __expf(-g));
        }

        // ---- update + packed f16 h write + norm/gate-dot partials ----
        const int pw = p ^ 1;
        float pn[4], gd[4];
        #pragma unroll
        for (int reg = 0; reg < 4; ++reg) {
            const int row = quad * 4 + reg;
            float sq = 0.f, dv = 0.f;
            float u2s[2];
            #pragma unroll
            for (int sub = 0; sub < NSUB; ++sub) {
                const float asum = acc[sub][0][reg] + acc[sub][1][reg];
                float ht = rn[reg] * asum + keysVc[reg][sub] + eWc[sub];
                ht = fmaxf(ht, 0.f);
                const float u2 = rn[reg] * upv[reg][sub] + gate[reg] * ht;
                upv[reg][sub] = u2;
                u2s[sub] = u2;
                sq += u2 * u2;
                dv += u2 * e_n[sub];
            }
            const u32 packed =
                ((u32)h_bits((_Float16)u2s[1]) << 16) |
                (u32)h_bits((_Float16)u2s[0]);
            *(u32*)&hF[pw][row][col2] = packed;
            pn[reg] = sq;
            gd[reg] = dv;
        }

        // ---- reload step-invariants IN PLACE (last use passed) ----
        if (sn >= 0) {
            const u32 w = *(const u32*)&eWh[sn][col2];
            eWc[0] = (float)f16_bits((u16)(w & 0xffff));
            eWc[1] = (float)f16_bits((u16)(w >> 16));
            ekv = *(const float4*)&ekl[sn][quad * 4];
        }

        // ---- value-splitting butterfly: 8 shuffles (R14-proven) ----
        {
            float v0 = pn[0], v1 = pn[1], v2 = pn[2], v3 = pn[3];
            float w0 = gd[0], w1 = gd[1], w2 = gd[2], w3 = gd[3];
            {   // xor 1
                const bool hi = (n & 1);
                float k0 = hi ? w0 : v0, x0 = hi ? v0 : w0;
                float k1 = hi ? w1 : v1, x1 = hi ? v1 : w1;
                float k2 = hi ? w2 : v2, x2 = hi ? v2 : w2;
                float k3 = hi ? w3 : v3, x3 = hi ? v3 : w3;
                v0 = k0 + __shfl_xor(x0, 1);
                v1 = k1 + __shfl_xor(x1, 1);
                v2 = k2 + __shfl_xor(x2, 1);
                v3 = k3 + __shfl_xor(x3, 1);
            }
            {   // xor 2
                const bool hi = (n & 2);
                float k0 = hi ? v2 : v0, x0 = hi ? v0 : v2;
                float k1 = hi ? v3 : v1, x1 = hi ? v1 : v3;
                v0 = k0 + __shfl_xor(x0, 2);
                v1 = k1 + __shfl_xor(x1, 2);
            }
            {   // xor 4
                const bool hi = (n & 4);
                float k0 = hi ? v1 : v0, x0 = hi ? v0 : v1;
                v0 = k0 + __shfl_xor(x0, 4);
            }
            v0 += __shfl_xor(v0, 8);
            if (n < 8) {
                const int vid = ((n & 1) << 2) | (n & 2) | ((n >> 2) & 1);
                const int row = quad * 4 + (vid & 3);
                float* dst = (vid & 4) ? &redG[q][row][wave]
                                       : &redN[q][row][wave];
                *dst = v0;
            }
        }

        __syncthreads();   // the ONLY loop barrier (R12-proven form)

        #pragma unroll
        for (int reg = 0; reg < 4; ++reg) {
            const float* rp = redN[q][quad * 4 + reg];
            const float4 r0 = *(const float4*)rp;
            const float4 r1 = *(const float4*)(rp + 4);
            rn[reg] = rsqrtf(fmaxf(r0.x + r0.y + r0.z + r0.w +
                                   r1.x + r1.y + r1.z + r1.w, 1e-12f));
        }
        p ^= 1; q ^= 1; first = false;
    }

    #pragma unroll
    for (int reg = 0; reg < 4; ++reg) {
        const size_t base = (size_t)(b * K + kh + quad * 4 + reg) * D;
        const float2 o2 = make_float2(rn[reg] * upv[reg][0],
                                      rn[reg] * upv[reg][1]);
        *(float2*)&out[base + col2] = o2;
    }
}

extern "C" void kernel_launch(void* const* d_in, const int* in_sizes, int n_in,
                              void* d_out, int out_size, void* d_ws, size_t ws_size,
                              hipStream_t stream) {
    const int*   prgrph = (const int*)d_in[0];
    const void*  pmask  = d_in[1];
    const float* keys   = (const float*)d_in[2];
    const float* E      = (const float*)d_in[3];
    const float* U      = (const float*)d_in[4];
    const float* V      = (const float*)d_in[5];
    const float* W      = (const float*)d_in[6];
    float* out = (float*)d_out;

    float* ws_enc  = (float*)d_ws;                       // B*S*D (8 MB)
    int*   ws_mask = (int*)(ws_enc + (size_t)B * S * D); // B*S

    embed_kernel<<<(B * S) / 4, 256, 0, stream>>>(prgrph, E, pmask, ws_enc, ws_mask);
    recur_kernel<<<B * (K / KH), 512, 0, stream>>>(
        ws_enc, keys, W, V, U, ws_mask, out);
}

// Round 11
// 218.369 us; speedup vs baseline: 1.4681x; 1.4681x over previous
//
#include <hip/hip_runtime.h>

#define D 256
#define B 128
#define S 64
#define L 32
#define K 32
#define KH 16
#define NW 8      // waves per recur block (512 threads), 32 cols/wave
#define NSUB 2    // 2 adjacent cols per lane (col2 remap)
#define HSTR 260  // u16 stride (proven 0-conflict R7/R8)

typedef _Float16 f16x8 __attribute__((ext_vector_type(8)));  // 8 f16 in 4 VGPRs
typedef float f32x4 __attribute__((ext_vector_type(4)));
typedef unsigned short u16;
typedef unsigned int u32;

__device__ __forceinline__ u16 h_bits(_Float16 h) {
    union { _Float16 h; u16 u; } x; x.h = h; return x.u;
}
__device__ __forceinline__ _Float16 f16_bits(u16 v) {
    union { u16 u; _Float16 h; } x; x.u = v; return x.h;
}
// 8 contiguous floats -> f16 hi/lo fragments
__device__ __forceinline__ void cvt8(const float* p, f16x8& hi, f16x8& lo) {
    const float4 a = *(const float4*)p;
    const float4 b = *(const float4*)(p + 4);
    #pragma unroll
    for (int j = 0; j < 8; ++j) {
        const float v = (j < 4) ? ((const float*)&a)[j] : ((const float*)&b)[j - 4];
        const _Float16 vh = (_Float16)v;
        hi[j] = vh;
        lo[j] = (_Float16)(v - (float)vh);
    }
}
// 8 stride-D floats (weight column) -> f16 hi/lo fragments
__device__ __forceinline__ void cvt8s(const float* p, f16x8& hi, f16x8& lo) {
    #pragma unroll
    for (int j = 0; j < 8; ++j) {
        const float v = p[(size_t)j * D];
        const _Float16 vh = (_Float16)v;
        hi[j] = vh;
        lo[j] = (_Float16)(v - (float)vh);
    }
}

// ---------------------------------------------------------------------------
// embed_kernel (unchanged from R10, R1-proven): 2048 blocks, 4 sentences each,
// fused mask extraction, each enc line written ONCE (no XCD write storm).
// ---------------------------------------------------------------------------
__global__ __launch_bounds__(256) void embed_kernel(
    const int* __restrict__ prgrph, const float* __restrict__ E,
    const void* __restrict__ mraw,
    float* __restrict__ enc, int* __restrict__ mask_out) {
    const int t = threadIdx.x;
    const int g = t >> 6;
    const int c4 = t & 63;
    __shared__ int flag;
    __shared__ int smask[4];
    __shared__ int sidx[4][L];
    if (t == 0) flag = 0;
    __syncthreads();
    {
        const u32* w32 = (const u32*)mraw;
        int loc = 0;
        #pragma unroll
        for (int j = 0; j < 4; ++j)
            if (w32[t * 4 + j] > 1u) loc = 1;
        if (loc) flag = 1;   // benign race
    }
    if (t < 4 * L) sidx[t >> 5][t & 31] = prgrph[(size_t)blockIdx.x * 4 * L + t];
    __syncthreads();
    if (t < 4) {
        const int gi = blockIdx.x * 4 + t;
        const int mv = (flag != 0)
            ? (int)((const unsigned char*)mraw)[(size_t)gi * L]
            : ((const int*)mraw)[(size_t)gi * L];
        smask[t] = mv;
        mask_out[gi] = mv;
    }
    __syncthreads();
    if (!smask[g]) return;
    const float4* E4 = (const float4*)E;
    float4 a = make_float4(0.f, 0.f, 0.f, 0.f);
    #pragma unroll
    for (int l = 0; l < L; ++l) {
        const float4 v = E4[(size_t)sidx[g][l] * (D / 4) + c4];
        a.x += v.x; a.y += v.y; a.z += v.z; a.w += v.w;
    }
    *(float4*)&enc[(size_t)(blockIdx.x * 4 + g) * D + c4 * 4] = a;
}

// ---------------------------------------------------------------------------
// R20 recur_kernel: R10's structure with a SPILL-FREE prologue. R10's 228µs
// came from scratch spills (WRITE_SIZE 167MB vs 4MB true output): Kh/Kl (64
// VGPR) live across the eW phase's Bh/Bl (64 VGPR) blew the 128-VGPR cap of
// __launch_bounds__(512,2). Fix: phase-reorder + streaming frags so no two
// 64-reg fragment arrays coexist:
//   A) keysV: per-kt streamed K/V frags (~25 VGPR live) -> keysVc regs
//   B) ek: waves 0-3 only (one tile each, was x8-redundant), streamed (~30)
//   C) eW: ONLY Bh/Bl persistent (64) + streamed enc A-frags (~85 peak)
// MFMA math/layouts identical to R9/R10 (harness-verified, absmax 1.95e-3).
// Loop = R5/R7-proven 91µs body; eWc/ekv from LDS.
// R10-R12: KEEP __syncthreads. setprio negative (lockstep, m190).
// ---------------------------------------------------------------------------
__global__ __launch_bounds__(512, 2) void recur_kernel(
    const float* __restrict__ enc, const float* __restrict__ keys,
    const float* __restrict__ Wm, const float* __restrict__ Vm,
    const float* __restrict__ U, const int* __restrict__ mask,
    float* __restrict__ out) {
    const int b   = blockIdx.x >> 1;
    const int kh0 = (blockIdx.x & 1) * KH;
    const int t = threadIdx.x;
    const int wave = t >> 6, lane = t & 63;
    const int n = lane & 15, quad = lane >> 4;
    const int col2 = wave * 32 + 2 * n;

    __shared__ u16   hF[2][KH][HSTR];    // 16.6 KB
    __shared__ float redN[2][KH][NW];
    __shared__ float redG[2][KH][NW];
    __shared__ u16   eWh[S][260];        // 33.3 KB, eW rows in f16
    __shared__ float ekl[S][20];         // 5.1 KB

    // ---- Phase A: keysV = keys @ V -> keysVc[reg][sub] (streamed frags) ----
    float keysVc[4][NSUB];
    {
        f32x4 accV[NSUB];
        accV[0] = (f32x4){0.f, 0.f, 0.f, 0.f};
        accV[1] = (f32x4){0.f, 0.f, 0.f, 0.f};
        for (int kt = 0; kt < 8; ++kt) {
            f16x8 khf, klf;
            cvt8(keys + (size_t)(b * K + kh0 + n) * D + kt * 32 + quad * 8, khf, klf);
            #pragma unroll
            for (int sub = 0; sub < NSUB; ++sub) {
                f16x8 vh, vl;
                cvt8s(Vm + (size_t)(kt * 32 + quad * 8) * D + col2 + sub, vh, vl);
                accV[sub] = __builtin_amdgcn_mfma_f32_16x16x32_f16(khf, vh, accV[sub], 0, 0, 0);
                accV[sub] = __builtin_amdgcn_mfma_f32_16x16x32_f16(khf, vl, accV[sub], 0, 0, 0);
                accV[sub] = __builtin_amdgcn_mfma_f32_16x16x32_f16(klf, vh, accV[sub], 0, 0, 0);
            }
        }
        #pragma unroll
        for (int reg = 0; reg < 4; ++reg) {
            keysVc[reg][0] = accV[0][reg];
            keysVc[reg][1] = accV[1][reg];
        }
    }

    // ---- Phase B: ek = enc @ keys^T, waves 0-3, one 16-sentence tile each ----
    if (wave < 4) {
        const int tile = wave;
        f32x4 acc = (f32x4){0.f, 0.f, 0.f, 0.f};
        for (int kt = 0; kt < 8; ++kt) {
            f16x8 ah, al, khf, klf;
            cvt8(enc + (size_t)(b * S + tile * 16 + n) * D + kt * 32 + quad * 8, ah, al);
            cvt8(keys + (size_t)(b * K + kh0 + n) * D + kt * 32 + quad * 8, khf, klf);
            acc = __builtin_amdgcn_mfma_f32_16x16x32_f16(ah, khf, acc, 0, 0, 0);
            acc = __builtin_amdgcn_mfma_f32_16x16x32_f16(ah, klf, acc, 0, 0, 0);
            acc = __builtin_amdgcn_mfma_f32_16x16x32_f16(al, khf, acc, 0, 0, 0);
        }
        #pragma unroll
        for (int reg = 0; reg < 4; ++reg)
            ekl[tile * 16 + quad * 4 + reg][n] = acc[reg];
    }

    // ---- Phase C: eW = enc @ W; ONLY Bh/Bl persistent (64 VGPR) ----
    {
        f16x8 Bh[NSUB][8], Bl[NSUB][8];
        #pragma unroll
        for (int sub = 0; sub < NSUB; ++sub)
            #pragma unroll
            for (int kt = 0; kt < 8; ++kt)
                cvt8s(Wm + (size_t)(kt * 32 + quad * 8) * D + col2 + sub,
                      Bh[sub][kt], Bl[sub][kt]);
        #pragma unroll
        for (int tile = 0; tile < 4; ++tile) {
            f32x4 acc[NSUB];
            acc[0] = (f32x4){0.f, 0.f, 0.f, 0.f};
            acc[1] = (f32x4){0.f, 0.f, 0.f, 0.f};
            for (int kt = 0; kt < 8; ++kt) {
                f16x8 ah, al;
                cvt8(enc + (size_t)(b * S + tile * 16 + n) * D + kt * 32 + quad * 8, ah, al);
                #pragma unroll
                for (int sub = 0; sub < NSUB; ++sub) {
                    acc[sub] = __builtin_amdgcn_mfma_f32_16x16x32_f16(ah, Bh[sub][kt], acc[sub], 0, 0, 0);
                    acc[sub] = __builtin_amdgcn_mfma_f32_16x16x32_f16(ah, Bl[sub][kt], acc[sub], 0, 0, 0);
                    acc[sub] = __builtin_amdgcn_mfma_f32_16x16x32_f16(al, Bh[sub][kt], acc[sub], 0, 0, 0);
                }
            }
            #pragma unroll
            for (int reg = 0; reg < 4; ++reg) {
                const u32 packed =
                    ((u32)h_bits((_Float16)acc[1][reg]) << 16) |
                    (u32)h_bits((_Float16)acc[0][reg]);
                *(u32*)&eWh[tile * 16 + quad * 4 + reg][col2] = packed;
            }
        }
    }

    __syncthreads();   // eWh/ekl staged for the loop

    // ---- preload U B-fragments (f16 hi/lo): 128 AGPRs, pinned ----
    f16x8 Uhi[NSUB][8], Ulo[NSUB][8];
    #pragma unroll
    for (int sub = 0; sub < NSUB; ++sub) {
        const int col = col2 + sub;
        #pragma unroll
        for (int kt = 0; kt < 8; ++kt) {
            #pragma unroll
            for (int j = 0; j < 8; ++j) {
                const int k = kt * 32 + quad * 8 + j;
                const float u = U[(size_t)k * D + col];
                const _Float16 uh = (_Float16)u;
                Uhi[sub][kt][j] = uh;
                Ulo[sub][kt][j] = (_Float16)(u - (float)uh);
            }
        }
    }
    #pragma unroll
    for (int sub = 0; sub < NSUB; ++sub)
        #pragma unroll
        for (int kt = 0; kt < 8; ++kt)
            asm volatile("" : "+a"(Uhi[sub][kt]), "+a"(Ulo[sub][kt]));

    // ---- per-lane state ----
    float upv[4][NSUB];
    float rn[4];
    #pragma unroll
    for (int reg = 0; reg < 4; ++reg) {
        rn[reg] = 1.f;
        upv[reg][0] = 0.f; upv[reg][1] = 0.f;
    }

    const int* bm = mask + b * S;
    unsigned long long rem = __ballot(bm[lane] != 0);

    float eWc[NSUB];
    float4 ekv = make_float4(0.f, 0.f, 0.f, 0.f);
    eWc[0] = 0.f; eWc[1] = 0.f;
    if (rem) {
        const int s0 = (int)__builtin_ctzll(rem);
        const u32 w = *(const u32*)&eWh[s0][col2];
        eWc[0] = (float)f16_bits((u16)(w & 0xffff));
        eWc[1] = (float)f16_bits((u16)(w >> 16));
        ekv = *(const float4*)&ekl[s0][quad * 4];
    }

    int p = 0, q = 0;
    bool first = true;
    while (rem) {
        rem &= rem - 1;
        const int sn = rem ? (int)__builtin_ctzll(rem) : -1;

        // ---- issue next-step e load early (covered by MFMA) ----
        float e_n[NSUB];
        e_n[0] = 0.f; e_n[1] = 0.f;
        if (sn >= 0) {
            const float2 e2 = *(const float2*)&enc[(size_t)(b * S + sn) * D + col2];
            e_n[0] = e2.x; e_n[1] = e2.y;
        }

        // ---- MFMA: acc = h_prev @ (Uhi,Ulo), 4 indep chains of 8 ----
        f32x4 acc[NSUB][2];
        #pragma unroll
        for (int sub = 0; sub < NSUB; ++sub) {
            acc[sub][0] = (f32x4){0.f, 0.f, 0.f, 0.f};
            acc[sub][1] = (f32x4){0.f, 0.f, 0.f, 0.f};
        }
        if (!first) {
            #pragma unroll
            for (int kt = 0; kt < 8; ++kt) {
                const f16x8 av = *(const f16x8*)&hF[p][n][kt * 32 + quad * 8];
                #pragma unroll
                for (int sub = 0; sub < NSUB; ++sub) {
                    acc[sub][0] = __builtin_amdgcn_mfma_f32_16x16x32_f16(av, Uhi[sub][kt], acc[sub][0], 0, 0, 0);
                    acc[sub][1] = __builtin_amdgcn_mfma_f32_16x16x32_f16(av, Ulo[sub][kt], acc[sub][1], 0, 0, 0);
                }
            }
        }

        // ---- gate ----
        float gate[4];
        #pragma unroll
        for (int reg = 0; reg < 4; ++reg) {
            const float ekb = (reg == 0) ? ekv.x : (reg == 1) ? ekv.y
                            : (reg == 2) ? ekv.z : ekv.w;
            float g = ekb;
            if (!first) {
                const float* rg = redG[q ^ 1][quad * 4 + reg];
                const float4 g0 = *(const float4*)rg;
                const float4 g1 = *(const float4*)(rg + 4);
                g += rn[reg] * (g0.x + g0.y + g0.z + g0.w +
                                g1.x + g1.y + g1.z + g1.w);
            }
            gate[reg] = 1.f / (1.f + __expf(-g));
        }

        // ---- update + packed f16 h write + norm/gate-dot partials ----
        const int pw = p ^ 1;
        float pn[4], gd[4];
        #pragma unroll
        for (int reg = 0; reg < 4; ++reg) {
            const int row = quad * 4 + reg;
            float sq = 0.f, dv = 0.f;
            float u2s[2];
            #pragma unroll
            for (int sub = 0; sub < NSUB; ++sub) {
                const float asum = acc[sub][0][reg] + acc[sub][1][reg];
                float ht = rn[reg] * asum + keysVc[reg][sub] + eWc[sub];
                ht = fmaxf(ht, 0.f);
                const float u2 = rn[reg] * upv[reg][sub] + gate[reg] * ht;
                upv[reg][sub] = u2;
                u2s[sub] = u2;
                sq += u2 * u2;
                dv += u2 * e_n[sub];
            }
            const u32 packed =
                ((u32)h_bits((_Float16)u2s[1]) << 16) |
                (u32)h_bits((_Float16)u2s[0]);
            *(u32*)&hF[pw][row][col2] = packed;
            pn[reg] = sq;
            gd[reg] = dv;
        }

        // ---- reload step-invariants IN PLACE (last use passed) ----
        if (sn >= 0) {
            const u32 w = *(const u32*)&eWh[sn][col2];
            eWc[0] = (float)f16_bits((u16)(w & 0xffff));
            eWc[1] = (float)f16_bits((u16)(w >> 16));
            ekv = *(const float4*)&ekl[sn][quad * 4];
        }

        // ---- value-splitting butterfly: 8 shuffles (R14-proven) ----
        {
            float v0 = pn[0], v1 = pn[1], v2 = pn[2], v3 = pn[3];
            float w0 = gd[0], w1 = gd[1], w2 = gd[2], w3 = gd[3];
            {   // xor 1
                const bool hi = (n & 1);
                float k0 = hi ? w0 : v0, x0 = hi ? v0 : w0;
                float k1 = hi ? w1 : v1, x1 = hi ? v1 : w1;
                float k2 = hi ? w2 : v2, x2 = hi ? v2 : w2;
                float k3 = hi ? w3 : v3, x3 = hi ? v3 : w3;
                v0 = k0 + __shfl_xor(x0, 1);
                v1 = k1 + __shfl_xor(x1, 1);
                v2 = k2 + __shfl_xor(x2, 1);
                v3 = k3 + __shfl_xor(x3, 1);
            }
            {   // xor 2
                const bool hi = (n & 2);
                float k0 = hi ? v2 : v0, x0 = hi ? v0 : v2;
                float k1 = hi ? v3 : v1, x1 = hi ? v1 : v3;
                v0 = k0 + __shfl_xor(x0, 2);
                v1 = k1 + __shfl_xor(x1, 2);
            }
            {   // xor 4
                const bool hi = (n & 4);
                float k0 = hi ? v1 : v0, x0 = hi ? v0 : v1;
                v0 = k0 + __shfl_xor(x0, 4);
            }
            v0 += __shfl_xor(v0, 8);
            if (n < 8) {
                const int vid = ((n & 1) << 2) | (n & 2) | ((n >> 2) & 1);
                const int row = quad * 4 + (vid & 3);
                float* dst = (vid & 4) ? &redG[q][row][wave]
                                       : &redN[q][row][wave];
                *dst = v0;
            }
        }

        __syncthreads();   // the ONLY loop barrier (R12-proven form)

        #pragma unroll
        for (int reg = 0; reg < 4; ++reg) {
            const float* rp = redN[q][quad * 4 + reg];
            const float4 r0 = *(const float4*)rp;
            const float4 r1 = *(const float4*)(rp + 4);
            rn[reg] = rsqrtf(fmaxf(r0.x + r0.y + r0.z + r0.w +
                                   r1.x + r1.y + r1.z + r1.w, 1e-12f));
        }
        p ^= 1; q ^= 1; first = false;
    }

    #pragma unroll
    for (int reg = 0; reg < 4; ++reg) {
        const size_t base = (size_t)(b * K + kh0 + quad * 4 + reg) * D;
        const float2 o2 = make_float2(rn[reg] * upv[reg][0],
                                      rn[reg] * upv[reg][1]);
        *(float2*)&out[base + col2] = o2;
    }
}

extern "C" void kernel_launch(void* const* d_in, const int* in_sizes, int n_in,
                              void* d_out, int out_size, void* d_ws, size_t ws_size,
                              hipStream_t stream) {
    const int*   prgrph = (const int*)d_in[0];
    const void*  pmask  = d_in[1];
    const float* keys   = (const float*)d_in[2];
    const float* E      = (const float*)d_in[3];
    const float* U      = (const float*)d_in[4];
    const float* V      = (const float*)d_in[5];
    const float* W      = (const float*)d_in[6];
    float* out = (float*)d_out;

    float* ws_enc  = (float*)d_ws;                       // B*S*D (8 MB)
    int*   ws_mask = (int*)(ws_enc + (size_t)B * S * D); // B*S

    embed_kernel<<<(B * S) / 4, 256, 0, stream>>>(prgrph, E, pmask, ws_enc, ws_mask);
    recur_kernel<<<B * (K / KH), 512, 0, stream>>>(
        ws_enc, keys, W, V, U, ws_mask, out);
}